// Round 3
// baseline (300.141 us; speedup 1.0000x reference)
//
#include <hip/hip_runtime.h>

// MHSA. Inputs fp32, output fp32. B=4, T=2048, D=1024, H=16, hd=64.
// R10: QKV GEMM -> 256x256 8-phase-style pipelined kernel (T2+T3+T4+T5):
//  BK=64, 8 waves (512 thr), 2x64KB LDS dbuf, 4 quadrant-phases per K-tile,
//  1 half-tile gload_lds prefetch pair per phase, counted vmcnt (4/2, never 0
//  in steady loop) placed BEFORE phase-end barriers (barrier certifies all
//  waves' waits -> cross-wave staging safe), st_16x32 swizzle via
//  inverse-swizzled global source + swizzled ds_read, setprio around MFMA,
//  bijective XCD block swizzle. gemm<1> (proj, N=1024) stays on 128^2.

typedef __attribute__((ext_vector_type(8))) short bf16x8;
typedef __attribute__((ext_vector_type(8))) unsigned short u16x8;
typedef __attribute__((ext_vector_type(4))) float f32x4;
typedef __attribute__((ext_vector_type(16))) float f32x16;

#define DEV static __device__ __forceinline__
#define SBAR __builtin_amdgcn_sched_barrier(0)
#define WBAR __builtin_amdgcn_s_barrier()

DEV unsigned short f2b(float f) {  // RTNE f32 -> bf16
  union { float f; unsigned int i; } v; v.f = f;
  unsigned int x = v.i;
  return (unsigned short)((x + 0x7FFFu + ((x >> 16) & 1u)) >> 16);
}

DEV f32x4 mfma16(bf16x8 a, bf16x8 b, f32x4 c) {
  return __builtin_amdgcn_mfma_f32_16x16x32_bf16(a, b, c, 0, 0, 0);
}
DEV f32x16 mfma32(bf16x8 a, bf16x8 b, f32x16 c) {
  return __builtin_amdgcn_mfma_f32_32x32x16_bf16(a, b, c, 0, 0, 0);
}

DEV void gl_lds16(const unsigned short* g, unsigned short* l) {
  __builtin_amdgcn_global_load_lds(
      (const __attribute__((address_space(1))) unsigned int*)g,
      (__attribute__((address_space(3))) unsigned int*)l, 16, 0, 0);
}

// cvt two f32 pairs to packed bf16, then swap upper-half(a) <-> lower-half(b)
// across the wave. Yields two A-frag words (see layout notes in attn).
DEV void pk_swap(float a0, float a1, float b0, float b1,
                 unsigned int& w_lo, unsigned int& w_hi) {
  unsigned int a, b;
  asm("v_cvt_pk_bf16_f32 %0, %1, %2" : "=v"(a) : "v"(a0), "v"(a1));
  asm("v_cvt_pk_bf16_f32 %0, %1, %2" : "=v"(b) : "v"(b0), "v"(b1));
  asm("v_permlane32_swap_b32 %0, %1" : "+v"(a), "+v"(b));
  w_lo = a; w_hi = b;
}

// ---------------------------------------------------------------- convert
__global__ __launch_bounds__(256) void f32_to_bf16(
    const float* __restrict__ in, unsigned short* __restrict__ out, int n4) {
  const int i = (blockIdx.x * 256 + threadIdx.x) * 4;
  if (i >= n4 * 4) return;
  const float4 v = *(const float4*)(in + i);
  ushort4 o;
  o.x = f2b(v.x); o.y = f2b(v.y); o.z = f2b(v.z); o.w = f2b(v.w);
  *(ushort4*)(out + i) = o;
}

// ---------------------------------------------------------------- transpose
__global__ __launch_bounds__(256) void transpose_f32_bf16(
    const float* __restrict__ in, unsigned short* __restrict__ out,
    int R, int C) {
  __shared__ float tile[32][33];
  const int tx = threadIdx.x & 31, ty = threadIdx.x >> 5;
  const int c0 = blockIdx.x * 32, r0 = blockIdx.y * 32;
#pragma unroll
  for (int i = 0; i < 32; i += 8)
    tile[ty + i][tx] = in[(size_t)(r0 + ty + i) * C + (c0 + tx)];
  __syncthreads();
#pragma unroll
  for (int i = 0; i < 32; i += 8)
    out[(size_t)(c0 + ty + i) * R + (r0 + tx)] = f2b(tile[tx][ty + i]);
}

// V [bh][t][d] -> Vt [bh][d][t], 64x64 bf16 tiles per block
__global__ __launch_bounds__(256) void vtrans(
    const unsigned short* __restrict__ in, unsigned short* __restrict__ out) {
  __shared__ __align__(16) unsigned short tile[64 * 72];
  const int tid = threadIdx.x;
  const int bh = blockIdx.y, t0 = blockIdx.x * 64;
  const unsigned short* src = in + (size_t)bh * 131072 + (size_t)t0 * 64;
  unsigned short* dst = out + (size_t)bh * 131072 + t0;
#pragma unroll
  for (int i = 0; i < 2; ++i) {
    const int c = tid + i * 256;           // 512 chunks of 8 elems
    u16x8 v = *(const u16x8*)(src + c * 8);
    *(u16x8*)&tile[(c >> 3) * 72 + (c & 7) * 8] = v;
  }
  __syncthreads();
#pragma unroll
  for (int i = 0; i < 2; ++i) {
    const int c = tid + i * 256;
    const int d = c >> 3, t8 = (c & 7) * 8;
    u16x8 o;
#pragma unroll
    for (int j = 0; j < 8; ++j) o[j] = tile[(t8 + j) * 72 + d];
    *(u16x8*)(dst + (size_t)d * 2048 + t8) = o;
  }
}

#define QSCALE 0.18033688f  // 0.125 * log2(e)

// ---------------------------------------------------------------- GEMM 256^2
// C[M,N] = A[M,K]*Bt[N,K]^T + bias, scattered to Q/K/V bf16 [b,h,t,d].
// 8 waves: wr=w>>2 (M half, 128 rows), wc=w&3 (N quarter, 64 cols).
// LDS tile [256][64] bf16, st_16x32 swizzle: byte ^= ((byte>>9)&1)<<5,
// i.e. elem col c -> c ^ (((r>>2)&1)<<4). gload_lds writes linear; global
// source col pre-swizzled (involution). Loads per tile (8, issue order):
//   q0: B rows 0-127 (2), q1: B rows 128-255 (2),
//   q2: A rows 0-63 + 128-191 (2), q3: A rows 64-127 + 192-255 (2).
// Quadrant-phase q computes acc rows mi=2q,2q+1 (A rows wm+q*32..+32).
// Waits: q1-end vmcnt(4) [certifies THIS tile's A rows 64-127/192-255],
//        q3-end vmcnt(2) [certifies NEXT tile's B + A rows 0-63/128-191];
// both BEFORE the phase-end barrier so the barrier certifies all waves.
#define STAGE(dst, src, kcol, li)                                        \
  do {                                                                   \
    const int ch_ = (li) * 512 + tid;                                    \
    const int r_ = ch_ >> 3, s_ = ch_ & 7;                               \
    const int cs_ = (s_ ^ (((r_ >> 2) & 1) << 1)) << 3;                  \
    gl_lds16((src) + (size_t)r_ * K + (kcol) + cs_, &(dst)[ch_ * 8]);    \
  } while (0)

DEV bf16x8 rdfrag(const unsigned short* base, int r, int ks, int g) {
  const int c = (ks * 32 + g * 8) ^ (((r >> 2) & 1) << 4);
  return *(const bf16x8*)&base[r * 64 + c];
}

__global__ __launch_bounds__(512, 2) void gemm256_qkv(
    const unsigned short* __restrict__ A, const unsigned short* __restrict__ Bt,
    const float* __restrict__ bias, unsigned short* __restrict__ out,
    int M, int N, int K) {
  __shared__ __align__(16) unsigned short As[2][16384];
  __shared__ __align__(16) unsigned short Bs[2][16384];
  const int tid = threadIdx.x;
  const int w = tid >> 6, l = tid & 63, g = l >> 4, ln = l & 15;
  const int wm = (w >> 2) * 128, wn = (w & 3) * 64;

  // bijective XCD swizzle (nwg = 384, %8 == 0)
  const int nwgx = gridDim.x;
  int wg = blockIdx.y * nwgx + blockIdx.x;
  const int cpx = (nwgx * gridDim.y) >> 3;
  wg = (wg & 7) * cpx + (wg >> 3);
  const int m0 = (wg / nwgx) * 256, n0 = (wg % nwgx) * 256;

  const unsigned short* Ab = A + (size_t)m0 * K;
  const unsigned short* Bb = Bt + (size_t)n0 * K;

  f32x4 acc[8][4];
#pragma unroll
  for (int i = 0; i < 8; ++i)
#pragma unroll
    for (int j = 0; j < 4; ++j) acc[i][j] = (f32x4){0.f, 0.f, 0.f, 0.f};

  // prologue: tile 0 fully staged, full drain
  STAGE(Bs[0], Bb, 0, 0); STAGE(Bs[0], Bb, 0, 1);
  STAGE(Bs[0], Bb, 0, 2); STAGE(Bs[0], Bb, 0, 3);
  STAGE(As[0], Ab, 0, 0); STAGE(As[0], Ab, 0, 2);
  STAGE(As[0], Ab, 0, 1); STAGE(As[0], Ab, 0, 3);
  asm volatile("s_waitcnt vmcnt(0)" ::: "memory");
  WBAR;

  const int NT = K >> 6;
  for (int T = 0; T < NT; ++T) {
    unsigned short* Acur = (unsigned short*)As[T & 1];
    unsigned short* Bcur = (unsigned short*)Bs[T & 1];
    unsigned short* Anxt = (unsigned short*)As[(T & 1) ^ 1];
    unsigned short* Bnxt = (unsigned short*)Bs[(T & 1) ^ 1];
    const bool hn = (T + 1) < NT;
    const int kn = (T + 1) * 64;

    bf16x8 bfr[4][2];
    // ---------------- q0: acc rows 0,1
    {
      bf16x8 aq[2][2];
#pragma unroll
      for (int mi = 0; mi < 2; ++mi)
#pragma unroll
        for (int ks = 0; ks < 2; ++ks)
          aq[mi][ks] = rdfrag(Acur, wm + (0 + mi) * 16 + ln, ks, g);
#pragma unroll
      for (int ni = 0; ni < 4; ++ni)
#pragma unroll
        for (int ks = 0; ks < 2; ++ks)
          bfr[ni][ks] = rdfrag(Bcur, wn + ni * 16 + ln, ks, g);
      if (hn) { STAGE(Bnxt, Bb, kn, 0); STAGE(Bnxt, Bb, kn, 1); }
      SBAR; WBAR; SBAR;
      __builtin_amdgcn_s_setprio(1);
#pragma unroll
      for (int ks = 0; ks < 2; ++ks)
#pragma unroll
        for (int mi = 0; mi < 2; ++mi)
#pragma unroll
          for (int ni = 0; ni < 4; ++ni)
            acc[0 + mi][ni] = mfma16(aq[mi][ks], bfr[ni][ks], acc[0 + mi][ni]);
      __builtin_amdgcn_s_setprio(0);
      SBAR; WBAR;
    }
    // ---------------- q1: acc rows 2,3 ; tail vmcnt certifies A hi-rows
    {
      bf16x8 aq[2][2];
#pragma unroll
      for (int mi = 0; mi < 2; ++mi)
#pragma unroll
        for (int ks = 0; ks < 2; ++ks)
          aq[mi][ks] = rdfrag(Acur, wm + (2 + mi) * 16 + ln, ks, g);
      if (hn) { STAGE(Bnxt, Bb, kn, 2); STAGE(Bnxt, Bb, kn, 3); }
      SBAR; WBAR; SBAR;
      __builtin_amdgcn_s_setprio(1);
#pragma unroll
      for (int ks = 0; ks < 2; ++ks)
#pragma unroll
        for (int mi = 0; mi < 2; ++mi)
#pragma unroll
          for (int ni = 0; ni < 4; ++ni)
            acc[2 + mi][ni] = mfma16(aq[mi][ks], bfr[ni][ks], acc[2 + mi][ni]);
      __builtin_amdgcn_s_setprio(0);
      SBAR;
      if (hn) asm volatile("s_waitcnt vmcnt(4)" ::: "memory");
      else    asm volatile("s_waitcnt vmcnt(0)" ::: "memory");
      SBAR; WBAR;
    }
    // ---------------- q2: acc rows 4,5
    {
      bf16x8 aq[2][2];
#pragma unroll
      for (int mi = 0; mi < 2; ++mi)
#pragma unroll
        for (int ks = 0; ks < 2; ++ks)
          aq[mi][ks] = rdfrag(Acur, wm + (4 + mi) * 16 + ln, ks, g);
      if (hn) { STAGE(Anxt, Ab, kn, 0); STAGE(Anxt, Ab, kn, 2); }
      SBAR; WBAR; SBAR;
      __builtin_amdgcn_s_setprio(1);
#pragma unroll
      for (int ks = 0; ks < 2; ++ks)
#pragma unroll
        for (int mi = 0; mi < 2; ++mi)
#pragma unroll
          for (int ni = 0; ni < 4; ++ni)
            acc[4 + mi][ni] = mfma16(aq[mi][ks], bfr[ni][ks], acc[4 + mi][ni]);
      __builtin_amdgcn_s_setprio(0);
      SBAR; WBAR;
    }
    // ---------------- q3: acc rows 6,7 ; tail vmcnt certifies next tile
    {
      bf16x8 aq[2][2];
#pragma unroll
      for (int mi = 0; mi < 2; ++mi)
#pragma unroll
        for (int ks = 0; ks < 2; ++ks)
          aq[mi][ks] = rdfrag(Acur, wm + (6 + mi) * 16 + ln, ks, g);
      if (hn) { STAGE(Anxt, Ab, kn, 1); STAGE(Anxt, Ab, kn, 3); }
      SBAR; WBAR; SBAR;
      __builtin_amdgcn_s_setprio(1);
#pragma unroll
      for (int ks = 0; ks < 2; ++ks)
#pragma unroll
        for (int mi = 0; mi < 2; ++mi)
#pragma unroll
          for (int ni = 0; ni < 4; ++ni)
            acc[6 + mi][ni] = mfma16(aq[mi][ks], bfr[ni][ks], acc[6 + mi][ni]);
      __builtin_amdgcn_s_setprio(0);
      SBAR;
      if (hn) asm volatile("s_waitcnt vmcnt(2)" ::: "memory");
      SBAR; WBAR;
    }
  }

  // epilogue: scatter bf16 to Q/K/V [b,h,t,d] (Q prescaled)
#pragma unroll
  for (int mi = 0; mi < 8; ++mi) {
#pragma unroll
    for (int ni = 0; ni < 4; ++ni) {
      const int row0 = m0 + wm + mi * 16 + 4 * g;
      const int col = n0 + wn + ni * 16 + ln;
      const float bv = bias[col];
      const int which = col >> 10;           // 0=Q 1=K 2=V
      const int h = (col >> 6) & 15;
      const int dd = col & 63;
      unsigned short* dst = out + (size_t)which * 8388608u;
#pragma unroll
      for (int r = 0; r < 4; ++r) {
        float v = acc[mi][ni][r] + bv;
        const int row = row0 + r;
        const int b = row >> 11, t = row & 2047;
        if (which == 0) v *= QSCALE;
        dst[(((size_t)(b * 16 + h)) * 2048 + t) * 64 + dd] = f2b(v);
      }
    }
  }
}

// ---------------------------------------------------------------- GEMM 128^2
// C[M,N] = A[M,K]*Bt[N,K]^T + bias, fp32 row-major out (final projection).
__global__ __launch_bounds__(256, 2) void gemm_bt(
    const unsigned short* __restrict__ A, const unsigned short* __restrict__ Bt,
    const float* __restrict__ bias, float* __restrict__ out,
    int M, int N, int K) {
  __shared__ __align__(16) unsigned short As[128 * 32];
  __shared__ __align__(16) unsigned short Bs[128 * 32];
  const int tid = threadIdx.x;
  const int w = tid >> 6, l = tid & 63, g = l >> 4, ln = l & 15;
  const int m0 = blockIdx.y * 128, n0 = blockIdx.x * 128;
  const int wm = (w & 1) * 64, wn = (w >> 1) * 64;

  f32x4 acc[4][4];
#pragma unroll
  for (int i = 0; i < 4; ++i)
#pragma unroll
    for (int j = 0; j < 4; ++j) acc[i][j] = (f32x4){0.f, 0.f, 0.f, 0.f};

  const unsigned short* Ab = A + (size_t)m0 * K;
  const unsigned short* Bb = Bt + (size_t)n0 * K;
  const int c0 = tid, c1 = tid + 256;
  const int ar0 = c0 >> 2, ak0 = (c0 & 3) * 8;
  const int ar1 = c1 >> 2, ak1 = (c1 & 3) * 8;

  for (int k0 = 0; k0 < K; k0 += 32) {
    gl_lds16(Ab + (size_t)ar0 * K + k0 + ak0, &As[c0 * 8]);
    gl_lds16(Ab + (size_t)ar1 * K + k0 + ak1, &As[c1 * 8]);
    gl_lds16(Bb + (size_t)ar0 * K + k0 + ak0, &Bs[c0 * 8]);
    gl_lds16(Bb + (size_t)ar1 * K + k0 + ak1, &Bs[c1 * 8]);
    __syncthreads();
    bf16x8 af[4], bf[4];
#pragma unroll
    for (int mi = 0; mi < 4; ++mi)
      af[mi] = *(const bf16x8*)&As[(wm + mi * 16 + ln) * 32 + g * 8];
#pragma unroll
    for (int ni = 0; ni < 4; ++ni)
      bf[ni] = *(const bf16x8*)&Bs[(wn + ni * 16 + ln) * 32 + g * 8];
#pragma unroll
    for (int mi = 0; mi < 4; ++mi)
#pragma unroll
      for (int ni = 0; ni < 4; ++ni)
        acc[mi][ni] = mfma16(af[mi], bf[ni], acc[mi][ni]);
    __syncthreads();
  }

#pragma unroll
  for (int mi = 0; mi < 4; ++mi) {
#pragma unroll
    for (int ni = 0; ni < 4; ++ni) {
      const int row0 = m0 + wm + mi * 16 + 4 * g;
      const int col = n0 + wn + ni * 16 + ln;
      const float bv = bias[col];
#pragma unroll
      for (int r = 0; r < 4; ++r)
        out[(size_t)(row0 + r) * N + col] = acc[mi][ni][r] + bv;
    }
  }
}

// ---------------------------------------------------------------- attention
// One block per (bh, 128-q tile); 4 waves, wave w owns q rows [32w, 32w+32).
// mfma 32x32x16. Q prescaled (log2 domain), no online max, deferred
// l-normalization.
// SWAPPED QK^T: S^T = mfma32(K_frag, Q_frag) -> C/D col=l&31 is q, rows are
// keys at crow(r,lh)=(r&3)+8*(r>>2)+4*lh. Each lane owns P[q=l32][32 keys/nb].
// PV A-frag (m=q=l&31, k=lh*8+j) built in-register via pk_swap.
// Row-sums: os = mfma32(ap[ks], ones, os) -> os[r] = lsum(q=crow(r,lh)),
// identical layout to o[db][r]; epilogue needs no shuffles.
__global__ __launch_bounds__(256, 2) void attn(
    const unsigned short* __restrict__ Q, const unsigned short* __restrict__ K,
    const unsigned short* __restrict__ Vtg, unsigned short* __restrict__ Y) {
  __shared__ __align__(16) unsigned short Qs[128 * 72];
  __shared__ __align__(16) unsigned short Ks[64 * 72];     // [key][d]
  __shared__ __align__(16) unsigned short Vt[64 * 72];     // [d][key]

  const int tid = threadIdx.x;
  const int w = tid >> 6, l = tid & 63;
  const int l32 = l & 31, lh = l >> 5;       // half-wave select
  const int bh = blockIdx.y;
  const int q0 = blockIdx.x * 128;

  const unsigned short* Qb = Q + (size_t)bh * 131072;    // [t][d]
  const unsigned short* Kb = K + (size_t)bh * 131072;    // [t][d]
  const unsigned short* Vb = Vtg + (size_t)bh * 131072;  // [d][t]

  // stage Q: 128x64 bf16 -> stride-72 rows
#pragma unroll
  for (int i = 0; i < 4; ++i) {
    const int c = tid + i * 256;   // 1024 chunks
    u16x8 v = *(const u16x8*)(Qb + (size_t)q0 * 64 + c * 8);
    *(u16x8*)&Qs[(c >> 3) * 72 + (c & 7) * 8] = v;
  }
  __syncthreads();
  // hoist Q fragments (B-operand now; same (idx=l&31, k) mapping as A)
  bf16x8 aq[4];
#pragma unroll
  for (int kb = 0; kb < 4; ++kb)
    aq[kb] = *(const bf16x8*)&Qs[(w * 32 + l32) * 72 + kb * 16 + lh * 8];

  // ones B-frag (bf16 1.0 = 0x3F80) for the row-sum MFMA
  const short one_b = (short)0x3F80;
  const bf16x8 vones = (bf16x8){one_b, one_b, one_b, one_b,
                                one_b, one_b, one_b, one_b};

  f32x16 o[2], os;
#pragma unroll
  for (int db = 0; db < 2; ++db)
#pragma unroll
    for (int r = 0; r < 16; ++r) o[db][r] = 0.f;
#pragma unroll
  for (int r = 0; r < 16; ++r) os[r] = 0.f;

  for (int kt = 0; kt < 32; ++kt) {
    // stage K tile [key][d] and V tile [d][key] (V^T global)
#pragma unroll
    for (int i = 0; i < 2; ++i) {
      const int c = tid + i * 256;
      const int row = c >> 3, cc = (c & 7) * 8;
      u16x8 kv = *(const u16x8*)(Kb + (size_t)kt * 4096 + c * 8);
      u16x8 vv = *(const u16x8*)(Vb + (size_t)row * 2048 + kt * 64 + cc);
      *(u16x8*)&Ks[row * 72 + cc] = kv;
      *(u16x8*)&Vt[row * 72 + cc] = vv;
    }
    __syncthreads();

    // S^T = K Q^T : per wave 64k x 32q, two 32-key blocks (A=K, B=Q)
    f32x16 s[2];
#pragma unroll
    for (int nb = 0; nb < 2; ++nb) {
#pragma unroll
      for (int r = 0; r < 16; ++r) s[nb][r] = 0.f;
#pragma unroll
      for (int kb = 0; kb < 4; ++kb) {
        bf16x8 bk = *(const bf16x8*)&Ks[(nb * 32 + l32) * 72 + kb * 16 + lh * 8];
        s[nb] = mfma32(bk, aq[kb], s[nb]);
      }
    }

    // raw v_exp_f32 + in-register P->bf16 A-fragments (no LDS round-trip)
    bf16x8 ap[4];
#pragma unroll
    for (int nb = 0; nb < 2; ++nb) {
      float pe[16];
#pragma unroll
      for (int r = 0; r < 16; ++r)
        pe[r] = __builtin_amdgcn_exp2f(s[nb][r]);
      union { unsigned int wd[4]; bf16x8 v; } u0, u1;
      pk_swap(pe[0], pe[1], pe[4], pe[5], u0.wd[0], u0.wd[2]);
      pk_swap(pe[2], pe[3], pe[6], pe[7], u0.wd[1], u0.wd[3]);
      pk_swap(pe[8], pe[9], pe[12], pe[13], u1.wd[0], u1.wd[2]);
      pk_swap(pe[10], pe[11], pe[14], pe[15], u1.wd[1], u1.wd[3]);
      ap[2 * nb + 0] = u0.v;   // keys nb*32 + [0,16)
      ap[2 * nb + 1] = u1.v;   // keys nb*32 + [16,32)
    }

    // PV: A = P (in-register), B = V^T; row-sum on the MFMA pipe
#pragma unroll
    for (int ks = 0; ks < 4; ++ks) {
      os = mfma32(ap[ks], vones, os);
#pragma unroll
      for (int db = 0; db < 2; ++db) {
        bf16x8 bv = *(const bf16x8*)&Vt[(db * 32 + l32) * 72 + ks * 16 + lh * 8];
        o[db] = mfma32(ap[ks], bv, o[db]);
      }
    }
    __syncthreads();  // all waves done with Ks/Vt before next staging
  }

  // os[r] = sum over all keys of P[q=crow(r,lh)] -- same layout as o[db][r]
  float iv[16];
#pragma unroll
  for (int r = 0; r < 16; ++r) iv[r] = 1.f / os[r];

  // epilogue: y[b, t, h*64 + d]
  const int b = bh >> 4, h = bh & 15;
#pragma unroll
  for (int db = 0; db < 2; ++db)
#pragma unroll
    for (int r = 0; r < 16; ++r) {
      const int row = (r & 3) + 8 * (r >> 2) + 4 * lh;
      const int t = q0 + w * 32 + row;
      Y[(size_t)(b * 2048 + t) * 1024 + h * 64 + db * 32 + l32] =
          f2b(o[db][r] * iv[r]);
    }
}

// ---------------------------------------------------------------- launch
extern "C" void kernel_launch(void* const* d_in, const int* in_sizes, int n_in,
                              void* d_out, int out_size, void* d_ws, size_t ws_size,
                              hipStream_t stream) {
  const float* x     = (const float*)d_in[0];
  const float* Wqkv  = (const float*)d_in[1];
  const float* bqkv  = (const float*)d_in[2];
  const float* Wproj = (const float*)d_in[3];
  const float* bproj = (const float*)d_in[4];
  float* out = (float*)d_out;
  unsigned short* ws = (unsigned short*)d_ws;

  unsigned short* xbf    = ws;
  unsigned short* Yw     = xbf;  // alias: x dead after gemm256_qkv
  unsigned short* WqkvT  = xbf + 8388608;
  unsigned short* WprojT = WqkvT + 3072 * 1024;
  unsigned short* Qw     = WprojT + 1024 * 1024;
  unsigned short* Kw     = Qw + 8388608;
  unsigned short* Vw     = Kw + 8388608;   // [b,h,t,d]
  unsigned short* Vtw    = Vw + 8388608;   // [b,h,d,t]

  f32_to_bf16<<<8192, 256, 0, stream>>>(x, xbf, 2097152);
  transpose_f32_bf16<<<dim3(96, 32), 256, 0, stream>>>(Wqkv, WqkvT, 1024, 3072);
  transpose_f32_bf16<<<dim3(32, 32), 256, 0, stream>>>(Wproj, WprojT, 1024, 1024);
  gemm256_qkv<<<dim3(12, 32), 512, 0, stream>>>(xbf, WqkvT, bqkv, Qw, 8192, 3072, 1024);
  vtrans<<<dim3(32, 64), 256, 0, stream>>>(Vw, Vtw);
  attn<<<dim3(16, 64), 256, 0, stream>>>(Qw, Kw, Vtw, Yw);
  gemm_bt<<<dim3(8, 64), 256, 0, stream>>>(Yw, WprojT, bproj, out, 8192, 1024, 1024);
}

// Round 4
// 279.342 us; speedup vs baseline: 1.0745x; 1.0745x over previous
//
#include <hip/hip_runtime.h>

// MHSA. Inputs fp32, output fp32. B=4, T=2048, D=1024, H=16, hd=64.
// R11: (a) REVERT R10's gemm256 (net-regressed 291.5->300.1; back to proven
//      128^2 gemm_bt). (b) attn: K/V LDS double-buffer + T14 async-STAGE
//      split -- issue kt+1 global loads at loop top (hide HBM latency under
//      QK/softmax/PV), ds_write to alternate buffer at loop bottom, ONE
//      barrier per kt (was 2 + exposed vmcnt(0) stage). LDS 36.9->55.3 KB,
//      still 2 blocks/CU. Softmax stays fully in-register (R9).

typedef __attribute__((ext_vector_type(8))) short bf16x8;
typedef __attribute__((ext_vector_type(8))) unsigned short u16x8;
typedef __attribute__((ext_vector_type(4))) float f32x4;
typedef __attribute__((ext_vector_type(16))) float f32x16;

#define DEV static __device__ __forceinline__

DEV unsigned short f2b(float f) {  // RTNE f32 -> bf16
  union { float f; unsigned int i; } v; v.f = f;
  unsigned int x = v.i;
  return (unsigned short)((x + 0x7FFFu + ((x >> 16) & 1u)) >> 16);
}

DEV f32x4 mfma16(bf16x8 a, bf16x8 b, f32x4 c) {
  return __builtin_amdgcn_mfma_f32_16x16x32_bf16(a, b, c, 0, 0, 0);
}
DEV f32x16 mfma32(bf16x8 a, bf16x8 b, f32x16 c) {
  return __builtin_amdgcn_mfma_f32_32x32x16_bf16(a, b, c, 0, 0, 0);
}

DEV void gl_lds16(const unsigned short* g, unsigned short* l) {
  __builtin_amdgcn_global_load_lds(
      (const __attribute__((address_space(1))) unsigned int*)g,
      (__attribute__((address_space(3))) unsigned int*)l, 16, 0, 0);
}

// cvt two f32 pairs to packed bf16, then swap upper-half(a) <-> lower-half(b)
// across the wave. Yields two A-frag words (see layout notes in attn).
DEV void pk_swap(float a0, float a1, float b0, float b1,
                 unsigned int& w_lo, unsigned int& w_hi) {
  unsigned int a, b;
  asm("v_cvt_pk_bf16_f32 %0, %1, %2" : "=v"(a) : "v"(a0), "v"(a1));
  asm("v_cvt_pk_bf16_f32 %0, %1, %2" : "=v"(b) : "v"(b0), "v"(b1));
  asm("v_permlane32_swap_b32 %0, %1" : "+v"(a), "+v"(b));
  w_lo = a; w_hi = b;
}

// ---------------------------------------------------------------- convert
__global__ __launch_bounds__(256) void f32_to_bf16(
    const float* __restrict__ in, unsigned short* __restrict__ out, int n4) {
  const int i = (blockIdx.x * 256 + threadIdx.x) * 4;
  if (i >= n4 * 4) return;
  const float4 v = *(const float4*)(in + i);
  ushort4 o;
  o.x = f2b(v.x); o.y = f2b(v.y); o.z = f2b(v.z); o.w = f2b(v.w);
  *(ushort4*)(out + i) = o;
}

// ---------------------------------------------------------------- transpose
__global__ __launch_bounds__(256) void transpose_f32_bf16(
    const float* __restrict__ in, unsigned short* __restrict__ out,
    int R, int C) {
  __shared__ float tile[32][33];
  const int tx = threadIdx.x & 31, ty = threadIdx.x >> 5;
  const int c0 = blockIdx.x * 32, r0 = blockIdx.y * 32;
#pragma unroll
  for (int i = 0; i < 32; i += 8)
    tile[ty + i][tx] = in[(size_t)(r0 + ty + i) * C + (c0 + tx)];
  __syncthreads();
#pragma unroll
  for (int i = 0; i < 32; i += 8)
    out[(size_t)(c0 + ty + i) * R + (r0 + tx)] = f2b(tile[tx][ty + i]);
}

// V [bh][t][d] -> Vt [bh][d][t], 64x64 bf16 tiles per block
__global__ __launch_bounds__(256) void vtrans(
    const unsigned short* __restrict__ in, unsigned short* __restrict__ out) {
  __shared__ __align__(16) unsigned short tile[64 * 72];
  const int tid = threadIdx.x;
  const int bh = blockIdx.y, t0 = blockIdx.x * 64;
  const unsigned short* src = in + (size_t)bh * 131072 + (size_t)t0 * 64;
  unsigned short* dst = out + (size_t)bh * 131072 + t0;
#pragma unroll
  for (int i = 0; i < 2; ++i) {
    const int c = tid + i * 256;           // 512 chunks of 8 elems
    u16x8 v = *(const u16x8*)(src + c * 8);
    *(u16x8*)&tile[(c >> 3) * 72 + (c & 7) * 8] = v;
  }
  __syncthreads();
#pragma unroll
  for (int i = 0; i < 2; ++i) {
    const int c = tid + i * 256;
    const int d = c >> 3, t8 = (c & 7) * 8;
    u16x8 o;
#pragma unroll
    for (int j = 0; j < 8; ++j) o[j] = tile[(t8 + j) * 72 + d];
    *(u16x8*)(dst + (size_t)d * 2048 + t8) = o;
  }
}

// ---------------------------------------------------------------- GEMM
// C[M,N] = A[M,K]*Bt[N,K]^T + bias. 128x128 tile, BK=32, 4 waves, m97-style
// global_load_lds staging.
// MODE 0: scatter bf16 to Q/K/V, all [b,h,t,d] (Q prescaled 0.125*log2e).
// MODE 1: fp32 row-major output (final projection).
#define QSCALE 0.18033688f  // 0.125 * log2(e)
template <int MODE>
__global__ __launch_bounds__(256, 2) void gemm_bt(
    const unsigned short* __restrict__ A, const unsigned short* __restrict__ Bt,
    const float* __restrict__ bias, void* __restrict__ out_v,
    int M, int N, int K) {
  __shared__ __align__(16) unsigned short As[128 * 32];
  __shared__ __align__(16) unsigned short Bs[128 * 32];
  const int tid = threadIdx.x;
  const int w = tid >> 6, l = tid & 63, g = l >> 4, ln = l & 15;
  const int m0 = blockIdx.y * 128, n0 = blockIdx.x * 128;
  const int wm = (w & 1) * 64, wn = (w >> 1) * 64;

  f32x4 acc[4][4];
#pragma unroll
  for (int i = 0; i < 4; ++i)
#pragma unroll
    for (int j = 0; j < 4; ++j) acc[i][j] = (f32x4){0.f, 0.f, 0.f, 0.f};

  const unsigned short* Ab = A + (size_t)m0 * K;
  const unsigned short* Bb = Bt + (size_t)n0 * K;
  const int c0 = tid, c1 = tid + 256;
  const int ar0 = c0 >> 2, ak0 = (c0 & 3) * 8;
  const int ar1 = c1 >> 2, ak1 = (c1 & 3) * 8;

  for (int k0 = 0; k0 < K; k0 += 32) {
    gl_lds16(Ab + (size_t)ar0 * K + k0 + ak0, &As[c0 * 8]);
    gl_lds16(Ab + (size_t)ar1 * K + k0 + ak1, &As[c1 * 8]);
    gl_lds16(Bb + (size_t)ar0 * K + k0 + ak0, &Bs[c0 * 8]);
    gl_lds16(Bb + (size_t)ar1 * K + k0 + ak1, &Bs[c1 * 8]);
    __syncthreads();
    bf16x8 af[4], bf[4];
#pragma unroll
    for (int mi = 0; mi < 4; ++mi)
      af[mi] = *(const bf16x8*)&As[(wm + mi * 16 + ln) * 32 + g * 8];
#pragma unroll
    for (int ni = 0; ni < 4; ++ni)
      bf[ni] = *(const bf16x8*)&Bs[(wn + ni * 16 + ln) * 32 + g * 8];
#pragma unroll
    for (int mi = 0; mi < 4; ++mi)
#pragma unroll
      for (int ni = 0; ni < 4; ++ni)
        acc[mi][ni] = mfma16(af[mi], bf[ni], acc[mi][ni]);
    __syncthreads();
  }

#pragma unroll
  for (int mi = 0; mi < 4; ++mi) {
#pragma unroll
    for (int ni = 0; ni < 4; ++ni) {
      const int row0 = m0 + wm + mi * 16 + 4 * g;
      const int col = n0 + wn + ni * 16 + ln;
      const float bv = bias[col];
#pragma unroll
      for (int r = 0; r < 4; ++r) {
        float v = acc[mi][ni][r] + bv;
        const int row = row0 + r;
        if (MODE == 0) {
          const int which = col >> 10;           // 0=Q 1=K 2=V
          const int h = (col >> 6) & 15;
          const int dd = col & 63;
          const int b = row >> 11, t = row & 2047;
          unsigned short* dst = (unsigned short*)out_v + (size_t)which * 8388608u;
          if (which == 0) v *= QSCALE;
          dst[(((size_t)(b * 16 + h)) * 2048 + t) * 64 + dd] = f2b(v);
        } else {
          ((float*)out_v)[(size_t)row * N + col] = v;
        }
      }
    }
  }
}

// ---------------------------------------------------------------- attention
// One block per (bh, 128-q tile); 4 waves, wave w owns q rows [32w, 32w+32).
// mfma 32x32x16. Q prescaled (log2 domain), no online max, deferred
// l-normalization.
// SWAPPED QK^T: S^T = mfma32(K_frag, Q_frag) -> C/D col=l&31 is q, rows are
// keys at crow(r,lh)=(r&3)+8*(r>>2)+4*lh. Each lane owns P[q=l32][32 keys/nb].
// PV A-frag (m=q=l&31, k=lh*8+j) built in-register via pk_swap.
// Row-sums: os = mfma32(ap[ks], ones, os) -> os[r] = lsum(q=crow(r,lh)),
// identical layout to o[db][r]; epilogue needs no shuffles.
// R11: K/V double-buffered; kt+1 global loads issued BEFORE compute (T14),
// ds_write to the alternate buffer after compute; one barrier per kt.
// Hazards: write buf[n] at kt vs reads of buf[n] at kt-1 -> separated by
// kt-1's end barrier (WAR ok); write at kt vs reads at kt+1 -> kt's end
// barrier (RAW ok).
__global__ __launch_bounds__(256, 2) void attn(
    const unsigned short* __restrict__ Q, const unsigned short* __restrict__ K,
    const unsigned short* __restrict__ Vtg, unsigned short* __restrict__ Y) {
  __shared__ __align__(16) unsigned short Qs[128 * 72];
  __shared__ __align__(16) unsigned short Ks[2][64 * 72];  // [key][d]
  __shared__ __align__(16) unsigned short Vt[2][64 * 72];  // [d][key]

  const int tid = threadIdx.x;
  const int w = tid >> 6, l = tid & 63;
  const int l32 = l & 31, lh = l >> 5;       // half-wave select
  const int bh = blockIdx.y;
  const int q0 = blockIdx.x * 128;

  const unsigned short* Qb = Q + (size_t)bh * 131072;    // [t][d]
  const unsigned short* Kb = K + (size_t)bh * 131072;    // [t][d]
  const unsigned short* Vb = Vtg + (size_t)bh * 131072;  // [d][t]

  // per-thread staging coords: 2 chunks of 8 elems each for K and for V
  const int c0 = tid, c1 = tid + 256;
  const int r0 = c0 >> 3, s0 = (c0 & 7) * 8;
  const int r1 = c1 >> 3, s1 = (c1 & 7) * 8;

  // issue K/V tile-0 global loads, then stage Q (loads overlap Q staging)
  u16x8 ka = *(const u16x8*)(Kb + c0 * 8);
  u16x8 kb2 = *(const u16x8*)(Kb + c1 * 8);
  u16x8 va = *(const u16x8*)(Vb + (size_t)r0 * 2048 + s0);
  u16x8 vb2 = *(const u16x8*)(Vb + (size_t)r1 * 2048 + s1);
#pragma unroll
  for (int i = 0; i < 4; ++i) {
    const int c = tid + i * 256;   // 1024 chunks
    u16x8 qv = *(const u16x8*)(Qb + (size_t)q0 * 64 + c * 8);
    *(u16x8*)&Qs[(c >> 3) * 72 + (c & 7) * 8] = qv;
  }
  *(u16x8*)&Ks[0][r0 * 72 + s0] = ka;
  *(u16x8*)&Ks[0][r1 * 72 + s1] = kb2;
  *(u16x8*)&Vt[0][r0 * 72 + s0] = va;
  *(u16x8*)&Vt[0][r1 * 72 + s1] = vb2;
  __syncthreads();

  // hoist Q fragments (B-operand; (idx=l&31, k=lh*8+j) mapping)
  bf16x8 aq[4];
#pragma unroll
  for (int kb = 0; kb < 4; ++kb)
    aq[kb] = *(const bf16x8*)&Qs[(w * 32 + l32) * 72 + kb * 16 + lh * 8];

  // ones B-frag (bf16 1.0 = 0x3F80) for the row-sum MFMA
  const short one_b = (short)0x3F80;
  const bf16x8 vones = (bf16x8){one_b, one_b, one_b, one_b,
                                one_b, one_b, one_b, one_b};

  f32x16 o[2], os;
#pragma unroll
  for (int db = 0; db < 2; ++db)
#pragma unroll
    for (int r = 0; r < 16; ++r) o[db][r] = 0.f;
#pragma unroll
  for (int r = 0; r < 16; ++r) os[r] = 0.f;

  for (int kt = 0; kt < 32; ++kt) {
    const int cur = kt & 1;
    const unsigned short* Kc = Ks[cur];
    const unsigned short* Vc = Vt[cur];
    unsigned short* Kn = (unsigned short*)Ks[cur ^ 1];
    unsigned short* Vn = (unsigned short*)Vt[cur ^ 1];
    const bool more = (kt + 1) < 32;

    // T14: issue next tile's global loads first; waits land after compute
    u16x8 kn0, kn1, vn0, vn1;
    if (more) {
      const size_t kof = (size_t)(kt + 1) * 4096;
      const int vof = (kt + 1) * 64;
      kn0 = *(const u16x8*)(Kb + kof + c0 * 8);
      kn1 = *(const u16x8*)(Kb + kof + c1 * 8);
      vn0 = *(const u16x8*)(Vb + (size_t)r0 * 2048 + vof + s0);
      vn1 = *(const u16x8*)(Vb + (size_t)r1 * 2048 + vof + s1);
    }

    // S^T = K Q^T : per wave 64k x 32q, two 32-key blocks (A=K, B=Q)
    f32x16 s[2];
#pragma unroll
    for (int nb = 0; nb < 2; ++nb) {
#pragma unroll
      for (int r = 0; r < 16; ++r) s[nb][r] = 0.f;
#pragma unroll
      for (int kb = 0; kb < 4; ++kb) {
        bf16x8 bk = *(const bf16x8*)&Kc[(nb * 32 + l32) * 72 + kb * 16 + lh * 8];
        s[nb] = mfma32(bk, aq[kb], s[nb]);
      }
    }

    // raw v_exp_f32 + in-register P->bf16 A-fragments (no LDS round-trip)
    bf16x8 ap[4];
#pragma unroll
    for (int nb = 0; nb < 2; ++nb) {
      float pe[16];
#pragma unroll
      for (int r = 0; r < 16; ++r)
        pe[r] = __builtin_amdgcn_exp2f(s[nb][r]);
      union { unsigned int wd[4]; bf16x8 v; } u0, u1;
      pk_swap(pe[0], pe[1], pe[4], pe[5], u0.wd[0], u0.wd[2]);
      pk_swap(pe[2], pe[3], pe[6], pe[7], u0.wd[1], u0.wd[3]);
      pk_swap(pe[8], pe[9], pe[12], pe[13], u1.wd[0], u1.wd[2]);
      pk_swap(pe[10], pe[11], pe[14], pe[15], u1.wd[1], u1.wd[3]);
      ap[2 * nb + 0] = u0.v;   // keys nb*32 + [0,16)
      ap[2 * nb + 1] = u1.v;   // keys nb*32 + [16,32)
    }

    // PV: A = P (in-register), B = V^T; row-sum on the MFMA pipe
#pragma unroll
    for (int ks = 0; ks < 4; ++ks) {
      os = mfma32(ap[ks], vones, os);
#pragma unroll
      for (int db = 0; db < 2; ++db) {
        bf16x8 bv = *(const bf16x8*)&Vc[(db * 32 + l32) * 72 + ks * 16 + lh * 8];
        o[db] = mfma32(ap[ks], bv, o[db]);
      }
    }

    // write next tile into the alternate buffer (vmcnt waits land here)
    if (more) {
      *(u16x8*)&Kn[r0 * 72 + s0] = kn0;
      *(u16x8*)&Kn[r1 * 72 + s1] = kn1;
      *(u16x8*)&Vn[r0 * 72 + s0] = vn0;
      *(u16x8*)&Vn[r1 * 72 + s1] = vn1;
    }
    __syncthreads();  // RAW for kt+1's reads; WAR for kt+2's writes
  }

  // os[r] = sum over all keys of P[q=crow(r,lh)] -- same layout as o[db][r]
  float iv[16];
#pragma unroll
  for (int r = 0; r < 16; ++r) iv[r] = 1.f / os[r];

  // epilogue: y[b, t, h*64 + d]
  const int b = bh >> 4, h = bh & 15;
#pragma unroll
  for (int db = 0; db < 2; ++db)
#pragma unroll
    for (int r = 0; r < 16; ++r) {
      const int row = (r & 3) + 8 * (r >> 2) + 4 * lh;
      const int t = q0 + w * 32 + row;
      Y[(size_t)(b * 2048 + t) * 1024 + h * 64 + db * 32 + l32] =
          f2b(o[db][r] * iv[r]);
    }
}

// ---------------------------------------------------------------- launch
extern "C" void kernel_launch(void* const* d_in, const int* in_sizes, int n_in,
                              void* d_out, int out_size, void* d_ws, size_t ws_size,
                              hipStream_t stream) {
  const float* x     = (const float*)d_in[0];
  const float* Wqkv  = (const float*)d_in[1];
  const float* bqkv  = (const float*)d_in[2];
  const float* Wproj = (const float*)d_in[3];
  const float* bproj = (const float*)d_in[4];
  float* out = (float*)d_out;
  unsigned short* ws = (unsigned short*)d_ws;

  unsigned short* xbf    = ws;
  unsigned short* Yw     = xbf;  // alias: x dead after gemm_bt<0>
  unsigned short* WqkvT  = xbf + 8388608;
  unsigned short* WprojT = WqkvT + 3072 * 1024;
  unsigned short* Qw     = WprojT + 1024 * 1024;
  unsigned short* Kw     = Qw + 8388608;
  unsigned short* Vw     = Kw + 8388608;   // [b,h,t,d]
  unsigned short* Vtw    = Vw + 8388608;   // [b,h,d,t]

  f32_to_bf16<<<8192, 256, 0, stream>>>(x, xbf, 2097152);
  transpose_f32_bf16<<<dim3(96, 32), 256, 0, stream>>>(Wqkv, WqkvT, 1024, 3072);
  transpose_f32_bf16<<<dim3(32, 32), 256, 0, stream>>>(Wproj, WprojT, 1024, 1024);
  gemm_bt<0><<<dim3(24, 64), 256, 0, stream>>>(xbf, WqkvT, bqkv, Qw, 8192, 3072, 1024);
  vtrans<<<dim3(32, 64), 256, 0, stream>>>(Vw, Vtw);
  attn<<<dim3(16, 64), 256, 0, stream>>>(Qw, Kw, Vtw, Yw);
  gemm_bt<1><<<dim3(8, 64), 256, 0, stream>>>(Yw, WprojT, bproj, out, 8192, 1024, 1024);
}